// Round 4
// baseline (303.687 us; speedup 1.0000x reference)
//
#include <hip/hip_runtime.h>

#define B_ 128
#define N_ 289   // 17*17 regions
#define D_ 1024
#define T_ 32
#define GAMMA1 4.0f

// ---------------------------------------------------------------------------
// Kernel A: S[n,t] = sum_d ctx[b,n,d]*word[b,t,d]; softmax over t;
//           E[b,n,t] = exp(GAMMA1 * softmax_t(S)[n,t])
// grid (5, 128) : x = 64-row n-tile, y = batch.  block = 256.
// Thread map: i = tid/16 -> 4 n-rows (i*4+k); j = tid%16 -> t in {j, j+16}.
// ---------------------------------------------------------------------------
__global__ __launch_bounds__(256) void damsm_attn_a(
    const float* __restrict__ img, const float* __restrict__ word,
    float* __restrict__ E)
{
    __shared__ float s_ctx[64][68];   // stride 68: b128-aligned, <=2-way conflicts
    __shared__ float s_word[32][68];

    const int b   = blockIdx.y;
    const int n0  = blockIdx.x * 64;
    const int tid = threadIdx.x;
    const int i   = tid >> 4;   // 0..15 n-group
    const int j   = tid & 15;   // 0..15 t-group (t = j, j+16)

    const float* __restrict__ imgb  = img  + (size_t)(b * N_) * D_;
    const float* __restrict__ wordb = word + (size_t)(b * T_) * D_;

    float acc[4][2];
#pragma unroll
    for (int k = 0; k < 4; ++k) { acc[k][0] = 0.f; acc[k][1] = 0.f; }

    for (int d0 = 0; d0 < D_; d0 += 64) {
        // stage ctx tile: 64 rows x 64 floats (1024 float4, 4 per thread)
#pragma unroll
        for (int k = 0; k < 4; ++k) {
            int idx = tid + 256 * k;
            int nl  = idx >> 4;        // 0..63
            int dq  = idx & 15;        // 0..15 (float4)
            float4 v = make_float4(0.f, 0.f, 0.f, 0.f);
            int n = n0 + nl;
            if (n < N_)
                v = *(const float4*)(imgb + (size_t)n * D_ + d0 + dq * 4);
            *(float4*)(&s_ctx[nl][dq * 4]) = v;
        }
        // stage word tile: 32 x 64 (512 float4, 2 per thread)
#pragma unroll
        for (int k = 0; k < 2; ++k) {
            int idx = tid + 256 * k;
            int tl  = idx >> 4;        // 0..31
            int dq  = idx & 15;
            float4 v = *(const float4*)(wordb + (size_t)tl * D_ + d0 + dq * 4);
            *(float4*)(&s_word[tl][dq * 4]) = v;
        }
        __syncthreads();

#pragma unroll
        for (int d4 = 0; d4 < 16; ++d4) {
            float4 w0 = *(const float4*)(&s_word[j][d4 * 4]);
            float4 w1 = *(const float4*)(&s_word[j + 16][d4 * 4]);
#pragma unroll
            for (int k = 0; k < 4; ++k) {
                float4 c = *(const float4*)(&s_ctx[i * 4 + k][d4 * 4]);
                acc[k][0] = fmaf(c.x, w0.x, fmaf(c.y, w0.y,
                            fmaf(c.z, w0.z, fmaf(c.w, w0.w, acc[k][0]))));
                acc[k][1] = fmaf(c.x, w1.x, fmaf(c.y, w1.y,
                            fmaf(c.z, w1.z, fmaf(c.w, w1.w, acc[k][1]))));
            }
        }
        __syncthreads();
    }

    // softmax over t (32 values per row, in 16 lanes x 2 regs), then E=exp(4*p)
#pragma unroll
    for (int k = 0; k < 4; ++k) {
        float m = fmaxf(acc[k][0], acc[k][1]);
#pragma unroll
        for (int s = 1; s < 16; s <<= 1) m = fmaxf(m, __shfl_xor(m, s));
        float e0 = __expf(acc[k][0] - m);
        float e1 = __expf(acc[k][1] - m);
        float ssum = e0 + e1;
#pragma unroll
        for (int s = 1; s < 16; s <<= 1) ssum += __shfl_xor(ssum, s);
        float inv = 1.0f / ssum;
        float E0 = __expf(GAMMA1 * (e0 * inv));
        float E1 = __expf(GAMMA1 * (e1 * inv));
        int n = n0 + i * 4 + k;
        if (n < N_) {
            float* dst = E + (size_t)(b * N_ + n) * T_;
            dst[j]      = E0;
            dst[j + 16] = E1;
        }
    }
}

// ---------------------------------------------------------------------------
// Kernel B: out[b,d,t] = (1/colsum[b,t]) * sum_n ctx[b,n,d] * E[b,n,t]
// grid (8, 128) : x = 128-wide d-tile, y = batch.  block = 256.
// Thread map: p = tid/8 -> 4 d's (p*4+di); q = tid%8 -> 4 t's (q*4+tj).
// ---------------------------------------------------------------------------
__global__ __launch_bounds__(256) void damsm_attn_b(
    const float* __restrict__ img, const float* __restrict__ E,
    float* __restrict__ out)
{
    __shared__ float s_E[N_][T_];     // 36.1 KB, whole E[b]
    __shared__ float s_red[32][32];   // colsum partials
    __shared__ float s_csinv[T_];
    __shared__ float s_ctx[32][128];  // 16 KB n-chunk of ctx

    const int b   = blockIdx.y;
    const int d0  = blockIdx.x * 128;
    const int tid = threadIdx.x;
    const int p   = tid >> 3;   // 0..31 d-group
    const int q   = tid & 7;    // 0..7 t-group

    const float* __restrict__ Eb   = E   + (size_t)b * N_ * T_;
    const float* __restrict__ imgb = img + (size_t)(b * N_) * D_;

    // stage full E[b]: 2312 float4
    for (int idx = tid; idx < (N_ * T_) / 4; idx += 256)
        ((float4*)s_E)[idx] = ((const float4*)Eb)[idx];
    __syncthreads();

    // column sums: thread (p,q) sums n = p+32k for t = q*4..q*4+3
    {
        float4 part = make_float4(0.f, 0.f, 0.f, 0.f);
        for (int n = p; n < N_; n += 32) {
            float4 e = *(const float4*)(&s_E[n][q * 4]);
            part.x += e.x; part.y += e.y; part.z += e.z; part.w += e.w;
        }
        *(float4*)(&s_red[p][q * 4]) = part;
    }
    __syncthreads();
    if (tid < T_) {
        float s = 0.f;
        for (int pp = 0; pp < 32; ++pp) s += s_red[pp][tid];
        s_csinv[tid] = 1.0f / s;
    }
    __syncthreads();

    float acc[4][4];
#pragma unroll
    for (int a = 0; a < 4; ++a)
#pragma unroll
        for (int c = 0; c < 4; ++c) acc[a][c] = 0.f;

    // main loop over 9 chunks of 32 n-rows (288 rows), tail row 288 after
    for (int nc = 0; nc < 288; nc += 32) {
        // stage ctx chunk: 32 rows x 128 floats (1024 float4, 4/thread)
#pragma unroll
        for (int k = 0; k < 4; ++k) {
            int idx = tid + 256 * k;
            int nl  = idx >> 5;        // 0..31
            int dq  = idx & 31;        // 0..31 (float4)
            *(float4*)(&s_ctx[nl][dq * 4]) =
                *(const float4*)(imgb + (size_t)(nc + nl) * D_ + d0 + dq * 4);
        }
        __syncthreads();
#pragma unroll 4
        for (int nn = 0; nn < 32; ++nn) {
            float4 c = *(const float4*)(&s_ctx[nn][p * 4]);
            float4 e = *(const float4*)(&s_E[nc + nn][q * 4]);
            acc[0][0] = fmaf(c.x, e.x, acc[0][0]);
            acc[0][1] = fmaf(c.x, e.y, acc[0][1]);
            acc[0][2] = fmaf(c.x, e.z, acc[0][2]);
            acc[0][3] = fmaf(c.x, e.w, acc[0][3]);
            acc[1][0] = fmaf(c.y, e.x, acc[1][0]);
            acc[1][1] = fmaf(c.y, e.y, acc[1][1]);
            acc[1][2] = fmaf(c.y, e.z, acc[1][2]);
            acc[1][3] = fmaf(c.y, e.w, acc[1][3]);
            acc[2][0] = fmaf(c.z, e.x, acc[2][0]);
            acc[2][1] = fmaf(c.z, e.y, acc[2][1]);
            acc[2][2] = fmaf(c.z, e.z, acc[2][2]);
            acc[2][3] = fmaf(c.z, e.w, acc[2][3]);
            acc[3][0] = fmaf(c.w, e.x, acc[3][0]);
            acc[3][1] = fmaf(c.w, e.y, acc[3][1]);
            acc[3][2] = fmaf(c.w, e.z, acc[3][2]);
            acc[3][3] = fmaf(c.w, e.w, acc[3][3]);
        }
        __syncthreads();
    }
    // tail row n = 288
    {
        float4 e = *(const float4*)(&s_E[288][q * 4]);
        float4 c = *(const float4*)(imgb + (size_t)288 * D_ + d0 + p * 4);
        acc[0][0] = fmaf(c.x, e.x, acc[0][0]);
        acc[0][1] = fmaf(c.x, e.y, acc[0][1]);
        acc[0][2] = fmaf(c.x, e.z, acc[0][2]);
        acc[0][3] = fmaf(c.x, e.w, acc[0][3]);
        acc[1][0] = fmaf(c.y, e.x, acc[1][0]);
        acc[1][1] = fmaf(c.y, e.y, acc[1][1]);
        acc[1][2] = fmaf(c.y, e.z, acc[1][2]);
        acc[1][3] = fmaf(c.y, e.w, acc[1][3]);
        acc[2][0] = fmaf(c.z, e.x, acc[2][0]);
        acc[2][1] = fmaf(c.z, e.y, acc[2][1]);
        acc[2][2] = fmaf(c.z, e.z, acc[2][2]);
        acc[2][3] = fmaf(c.z, e.w, acc[2][3]);
        acc[3][0] = fmaf(c.w, e.x, acc[3][0]);
        acc[3][1] = fmaf(c.w, e.y, acc[3][1]);
        acc[3][2] = fmaf(c.w, e.z, acc[3][2]);
        acc[3][3] = fmaf(c.w, e.w, acc[3][3]);
    }

    // epilogue: scale by 1/colsum and store
    float4 ci = *(const float4*)(&s_csinv[q * 4]);
#pragma unroll
    for (int di = 0; di < 4; ++di) {
        int d = d0 + p * 4 + di;
        float4 v;
        v.x = acc[di][0] * ci.x;
        v.y = acc[di][1] * ci.y;
        v.z = acc[di][2] * ci.z;
        v.w = acc[di][3] * ci.w;
        *(float4*)(out + (size_t)(b * D_ + d) * T_ + q * 4) = v;
    }
}

extern "C" void kernel_launch(void* const* d_in, const int* in_sizes, int n_in,
                              void* d_out, int out_size, void* d_ws, size_t ws_size,
                              hipStream_t stream) {
    const float* img  = (const float*)d_in[0];   // [128,17,17,1024] fp32
    const float* word = (const float*)d_in[1];   // [128,32,1024]   fp32
    float* out = (float*)d_out;                  // [128,1024,32]   fp32
    float* E   = (float*)d_ws;                   // [128,289,32]    fp32 (4.7 MB)

    dim3 blk(256);
    dim3 grdA(5, 128);   // 5 n-tiles of 64 rows, 128 batches
    hipLaunchKernelGGL(damsm_attn_a, grdA, blk, 0, stream, img, word, E);
    dim3 grdB(8, 128);   // 8 d-tiles of 128, 128 batches
    hipLaunchKernelGGL(damsm_attn_b, grdB, blk, 0, stream, img, E, out);
}